// Round 4
// baseline (189.045 us; speedup 1.0000x reference)
//
#include <hip/hip_runtime.h>
#include <hip/hip_bf16.h>

// DepthLossWithMask: loss = sum(|output - label0| * label1) / count(label0 != 0)
// N = 16*15*256*256 = 15,728,640 floats -> n4 = 3,932,160 float4.
//
// R3 finding: VGPR=52 => compiler chunked the "24 loads in flight" into ~3
// serialized groups; occupancy 28%. R4: EPT=4 (12 dwordx4 = 48 payload VGPRs,
// actually allocatable) + 3840 blocks (exact cover, no bounds check) to get
// MLP from both wave count and per-wave outstanding loads.

#define REDUCE_THREADS 256
#define EPT 4   // float4 chunks per thread; block covers 256*4 = 1024 float4

struct Partial {
    float s;
    unsigned int c;
};

__global__ __launch_bounds__(REDUCE_THREADS)
void depth_loss_stage1(const float4* __restrict__ out,
                       const float4* __restrict__ l0,
                       const float4* __restrict__ l1,
                       Partial* __restrict__ partials) {
    const int base = blockIdx.x * (REDUCE_THREADS * EPT) + threadIdx.x;

    float4 o[EPT], a[EPT], w[EPT];
    // 12 independent global_load_dwordx4, all issued before any use.
    #pragma unroll
    for (int k = 0; k < EPT; ++k) o[k] = out[base + k * REDUCE_THREADS];
    #pragma unroll
    for (int k = 0; k < EPT; ++k) a[k] = l0[base + k * REDUCE_THREADS];
    #pragma unroll
    for (int k = 0; k < EPT; ++k) w[k] = l1[base + k * REDUCE_THREADS];

    float sum = 0.0f;
    unsigned int cnt = 0;
    #pragma unroll
    for (int k = 0; k < EPT; ++k) {
        sum += fabsf(o[k].x - a[k].x) * w[k].x;
        sum += fabsf(o[k].y - a[k].y) * w[k].y;
        sum += fabsf(o[k].z - a[k].z) * w[k].z;
        sum += fabsf(o[k].w - a[k].w) * w[k].w;
        cnt += (a[k].x != 0.0f) + (a[k].y != 0.0f) +
               (a[k].z != 0.0f) + (a[k].w != 0.0f);
    }

    // wave-64 butterfly reduce
    #pragma unroll
    for (int off = 32; off > 0; off >>= 1) {
        sum += __shfl_down(sum, off, 64);
        cnt += __shfl_down(cnt, off, 64);
    }

    __shared__ float        sv[REDUCE_THREADS / 64];
    __shared__ unsigned int sc[REDUCE_THREADS / 64];
    int lane = threadIdx.x & 63;
    int wid  = threadIdx.x >> 6;
    if (lane == 0) { sv[wid] = sum; sc[wid] = cnt; }
    __syncthreads();

    if (threadIdx.x == 0) {
        float bs = 0.0f;
        unsigned int bc = 0;
        #pragma unroll
        for (int i = 0; i < REDUCE_THREADS / 64; ++i) { bs += sv[i]; bc += sc[i]; }
        Partial p; p.s = bs; p.c = bc;
        partials[blockIdx.x] = p;   // plain 8B store, no contention
    }
}

__global__ __launch_bounds__(REDUCE_THREADS)
void depth_loss_stage2(const Partial* __restrict__ partials,
                       int nblocks,
                       float* __restrict__ out) {
    double sum = 0.0;
    unsigned int cnt = 0;
    for (int i = threadIdx.x; i < nblocks; i += REDUCE_THREADS) {
        Partial p = partials[i];
        sum += (double)p.s;
        cnt += p.c;
    }

    #pragma unroll
    for (int off = 32; off > 0; off >>= 1) {
        sum += __shfl_down(sum, off, 64);
        cnt += __shfl_down(cnt, off, 64);
    }

    __shared__ double       sv[REDUCE_THREADS / 64];
    __shared__ unsigned int sc[REDUCE_THREADS / 64];
    int lane = threadIdx.x & 63;
    int wid  = threadIdx.x >> 6;
    if (lane == 0) { sv[wid] = sum; sc[wid] = cnt; }
    __syncthreads();

    if (threadIdx.x == 0) {
        double bs = 0.0;
        unsigned int bc = 0;
        #pragma unroll
        for (int i = 0; i < REDUCE_THREADS / 64; ++i) { bs += sv[i]; bc += sc[i]; }
        out[0] = (bc == 0) ? 0.0f : (float)(bs / (double)bc);
    }
}

extern "C" void kernel_launch(void* const* d_in, const int* in_sizes, int n_in,
                              void* d_out, int out_size, void* d_ws, size_t ws_size,
                              hipStream_t stream) {
    const float* output = (const float*)d_in[0];
    const float* label0 = (const float*)d_in[1];
    const float* label1 = (const float*)d_in[2];
    int n = in_sizes[0];           // 15,728,640
    int n4 = n >> 2;               // 3,932,160 float4

    int per_block = REDUCE_THREADS * EPT;           // 1024 float4 per block
    int blocks = n4 / per_block;                    // 3840 (exact)

    Partial* partials = (Partial*)d_ws;             // 3840*8 = 30 KB, all written

    depth_loss_stage1<<<blocks, REDUCE_THREADS, 0, stream>>>(
        (const float4*)output, (const float4*)label0, (const float4*)label1,
        partials);

    depth_loss_stage2<<<1, REDUCE_THREADS, 0, stream>>>(
        partials, blocks, (float*)d_out);
}

// Round 5
// 189.035 us; speedup vs baseline: 1.0001x; 1.0001x over previous
//
#include <hip/hip_runtime.h>
#include <hip/hip_bf16.h>

// DepthLossWithMask: loss = sum(|output - label0| * label1) / count(label0 != 0)
// N = 16*15*256*256 = 15,728,640 floats -> n4 = 3,932,160 float4.
//
// R1-R4 finding: one-shot short-lived blocks -> occupancy 28%, ~4 wave-loads
// in flight per CU, stage1 pinned at ~67us (2.8 TB/s effective). R5: persistent
// grid-stride (2048 blocks = 8/CU resident, launch_bounds(256,8) caps VGPR at
// 64 so all 32 waves/CU fit) + explicit depth-2 software pipeline so every
// wave always has 3-6 dwordx4 loads outstanding.

#define REDUCE_THREADS 256
#define REDUCE_BLOCKS 2048

struct Partial {
    float s;
    unsigned int c;
};

__device__ __forceinline__ void accum(const float4& o, const float4& a,
                                      const float4& w, float& sum,
                                      unsigned int& cnt) {
    sum += fabsf(o.x - a.x) * w.x;
    sum += fabsf(o.y - a.y) * w.y;
    sum += fabsf(o.z - a.z) * w.z;
    sum += fabsf(o.w - a.w) * w.w;
    cnt += (a.x != 0.0f) + (a.y != 0.0f) + (a.z != 0.0f) + (a.w != 0.0f);
}

__global__ __launch_bounds__(REDUCE_THREADS, 8)
void depth_loss_stage1(const float4* __restrict__ out,
                       const float4* __restrict__ l0,
                       const float4* __restrict__ l1,
                       Partial* __restrict__ partials,
                       int n4) {
    const int stride = gridDim.x * REDUCE_THREADS;     // 524288
    int i = blockIdx.x * REDUCE_THREADS + threadIdx.x;

    float sum = 0.0f;
    unsigned int cnt = 0;

    if (i < n4) {
        // prologue: load iteration 0
        float4 o0 = out[i];
        float4 a0 = l0[i];
        float4 w0 = l1[i];
        int j = i + stride;
        // steady state: prefetch j while consuming the previous buffer.
        // unroll 2 => modulo register renaming, no v_mov shuffle.
        #pragma unroll 2
        for (; j < n4; j += stride) {
            float4 o1 = out[j];
            float4 a1 = l0[j];
            float4 w1 = l1[j];
            accum(o0, a0, w0, sum, cnt);
            o0 = o1; a0 = a1; w0 = w1;
        }
        accum(o0, a0, w0, sum, cnt);   // epilogue
    }

    // wave-64 butterfly reduce
    #pragma unroll
    for (int off = 32; off > 0; off >>= 1) {
        sum += __shfl_down(sum, off, 64);
        cnt += __shfl_down(cnt, off, 64);
    }

    __shared__ float        sv[REDUCE_THREADS / 64];
    __shared__ unsigned int sc[REDUCE_THREADS / 64];
    int lane = threadIdx.x & 63;
    int wid  = threadIdx.x >> 6;
    if (lane == 0) { sv[wid] = sum; sc[wid] = cnt; }
    __syncthreads();

    if (threadIdx.x == 0) {
        float bs = 0.0f;
        unsigned int bc = 0;
        #pragma unroll
        for (int k = 0; k < REDUCE_THREADS / 64; ++k) { bs += sv[k]; bc += sc[k]; }
        Partial p; p.s = bs; p.c = bc;
        partials[blockIdx.x] = p;   // plain 8B store, no contention
    }
}

__global__ __launch_bounds__(REDUCE_THREADS)
void depth_loss_stage2(const Partial* __restrict__ partials,
                       int nblocks,
                       float* __restrict__ out) {
    double sum = 0.0;
    unsigned int cnt = 0;
    for (int i = threadIdx.x; i < nblocks; i += REDUCE_THREADS) {
        Partial p = partials[i];
        sum += (double)p.s;
        cnt += p.c;
    }

    #pragma unroll
    for (int off = 32; off > 0; off >>= 1) {
        sum += __shfl_down(sum, off, 64);
        cnt += __shfl_down(cnt, off, 64);
    }

    __shared__ double       sv[REDUCE_THREADS / 64];
    __shared__ unsigned int sc[REDUCE_THREADS / 64];
    int lane = threadIdx.x & 63;
    int wid  = threadIdx.x >> 6;
    if (lane == 0) { sv[wid] = sum; sc[wid] = cnt; }
    __syncthreads();

    if (threadIdx.x == 0) {
        double bs = 0.0;
        unsigned int bc = 0;
        #pragma unroll
        for (int k = 0; k < REDUCE_THREADS / 64; ++k) { bs += sv[k]; bc += sc[k]; }
        out[0] = (bc == 0) ? 0.0f : (float)(bs / (double)bc);
    }
}

extern "C" void kernel_launch(void* const* d_in, const int* in_sizes, int n_in,
                              void* d_out, int out_size, void* d_ws, size_t ws_size,
                              hipStream_t stream) {
    const float* output = (const float*)d_in[0];
    const float* label0 = (const float*)d_in[1];
    const float* label1 = (const float*)d_in[2];
    int n = in_sizes[0];           // 15,728,640
    int n4 = n >> 2;               // 3,932,160 float4

    Partial* partials = (Partial*)d_ws;   // 2048*8 = 16 KB, every slot written

    depth_loss_stage1<<<REDUCE_BLOCKS, REDUCE_THREADS, 0, stream>>>(
        (const float4*)output, (const float4*)label0, (const float4*)label1,
        partials, n4);

    depth_loss_stage2<<<1, REDUCE_THREADS, 0, stream>>>(
        partials, REDUCE_BLOCKS, (float*)d_out);
}